// Round 4
// baseline (146.466 us; speedup 1.0000x reference)
//
#include <hip/hip_runtime.h>
#include <math.h>

#define NP 196
#define PI_F 3.14159265358979323846f
#define CS 4  // samples per thread in circuit kernel

// order-preserving float<->uint encoding (monotone: min of keys == key of min)
__device__ __forceinline__ unsigned fkey(float f) {
  unsigned u = __float_as_uint(f);
  return u ^ ((unsigned)((int)u >> 31) | 0x80000000u);
}
__device__ __forceinline__ float funkey(unsigned k) {
  unsigned u = (k & 0x80000000u) ? (k ^ 0x80000000u) : ~k;
  return __uint_as_float(u);
}

// ---------------------------------------------------------------------------
// K0 (grid=8): block 0 computes U (16x16 circuit matrix) and inits mn/mx;
// all blocks fill W2[k,p] = sum_c res_w[c]*cls_w[k, c*196+p].
// ---------------------------------------------------------------------------
__global__ void __launch_bounds__(256) precompute_kernel(
    const float* __restrict__ params, const float* __restrict__ res_w,
    const float* __restrict__ cls_w, float* __restrict__ U,
    float* __restrict__ W2, unsigned* __restrict__ mn,
    unsigned* __restrict__ mx) {
  const int tid = threadIdx.x;
  if (blockIdx.x == 0) {
    if (tid < NP) { mn[tid] = 0xFFFFFFFFu; mx[tid] = 0u; }
    if (tid < 16) {
      float cp[12], sp[12];
#pragma unroll
      for (int l = 0; l < 12; ++l) __sincosf(0.5f * params[l], &sp[l], &cp[l]);
      float st[16];
#pragma unroll
      for (int i = 0; i < 16; ++i) st[i] = 0.f;
      st[tid] = 1.f;  // basis vector e_j -> column j of U
#pragma unroll
      for (int l = 0; l < 3; ++l) {
#pragma unroll
        for (int q = 0; q < 4; ++q) {
          const float cq = cp[l * 4 + q], sq = sp[l * 4 + q];
          const int m = 8 >> q;
#pragma unroll
          for (int idx = 0; idx < 16; ++idx) {
            if (idx & m) continue;
            float v0 = st[idx], v1 = st[idx | m];
            st[idx] = cq * v0 - sq * v1;
            st[idx | m] = sq * v0 + cq * v1;
          }
        }
#pragma unroll
        for (int q = 0; q < 3; ++q) {
          const int mc = 8 >> q, mt = 4 >> q;
#pragma unroll
          for (int idx = 0; idx < 16; ++idx) {
            if ((idx & mc) && !(idx & mt)) {
              float t0 = st[idx];
              st[idx] = st[idx | mt];
              st[idx | mt] = t0;
            }
          }
        }
      }
#pragma unroll
      for (int i = 0; i < 16; ++i) U[i * 16 + tid] = st[i];
    }
  }
  for (int t = blockIdx.x * 256 + tid; t < 10 * NP; t += 8 * 256) {
    int k = t / NP, p = t - k * NP;
    float s = 0.f;
#pragma unroll
    for (int c = 0; c < 4; ++c) s += res_w[c] * cls_w[k * 784 + c * NP + p];
    W2[t] = s;
  }
}

// ---------------------------------------------------------------------------
// K1: per-patch-position min/max. Thread t<196 owns one float4 slot of the
// 784-float image (fully coalesced), register-reduces over `imgs` images,
// LDS row-combine, one global atomic per patch per block.
// ---------------------------------------------------------------------------
__global__ void __launch_bounds__(256) minmax_kernel(
    const float* __restrict__ x, unsigned* __restrict__ mn,
    unsigned* __restrict__ mx, int imgs, int B) {
  __shared__ float pmn[392], pmx[392];  // [row r(0..27)][col-pair jj(0..13)]
  const int t = threadIdx.x;
  const int img0 = blockIdx.x * imgs;
  if (t < NP) {
    const float* base = x + (size_t)img0 * 784 + 4 * t;
    float mn0 = 3.4e38f, mx0 = -3.4e38f, mn1 = 3.4e38f, mx1 = -3.4e38f;
    const int nimg = (img0 + imgs <= B) ? imgs : (B - img0);
#pragma unroll 4
    for (int m = 0; m < nimg; ++m) {
      float4 v = *(const float4*)(base + (size_t)m * 784);
      mn0 = fminf(mn0, fminf(v.x, v.y));
      mx0 = fmaxf(mx0, fmaxf(v.x, v.y));
      mn1 = fminf(mn1, fminf(v.z, v.w));
      mx1 = fmaxf(mx1, fmaxf(v.z, v.w));
    }
    const int r = (4 * t) / 28;
    const int jj = ((4 * t) - 28 * r) >> 1;  // even: covers jj and jj+1
    pmn[r * 14 + jj] = mn0;
    pmx[r * 14 + jj] = mx0;
    pmn[r * 14 + jj + 1] = mn1;
    pmx[r * 14 + jj + 1] = mx1;
  }
  __syncthreads();
  if (t < NP) {
    const int i = t / 14, j = t - i * 14;
    const int f0 = (2 * i) * 14 + j, f1 = f0 + 14;
    atomicMin(&mn[t], fkey(fminf(pmn[f0], pmn[f1])));
    atomicMax(&mx[t], fkey(fmaxf(pmx[f0], pmx[f1])));
  }
}

// ---------------------------------------------------------------------------
// K2: CS samples per thread. U staged in LDS (wave-uniform ds_read_b128
// broadcasts); per-patch min/scale staged in LDS. 256 FMA matvec per sample.
// gmeas[g] = float4(z0..z3) at g = b*196+p  (reference flat order b*784+4p+w).
// ---------------------------------------------------------------------------
__global__ void __launch_bounds__(256) circuit_kernel(
    const float* __restrict__ x, const unsigned* __restrict__ mnk,
    const unsigned* __restrict__ mxk, const float* __restrict__ Ug,
    float4* __restrict__ gmeas, int G) {
  __shared__ float sU[256];
  __shared__ float smn[NP], ssc[NP];
  const int tid = threadIdx.x;
  sU[tid] = Ug[tid];
  if (tid < NP) {
    const float mnv = funkey(mnk[tid]);
    const float mxv = funkey(mxk[tid]);
    smn[tid] = mnv;
    ssc[tid] = (0.5f * PI_F) / (mxv - mnv + 1e-8f);  // half-angle scale
  }
  __syncthreads();

  const int base = blockIdx.x * (256 * CS) + tid;
  float st[CS][16];
  int gi[CS];
#pragma unroll
  for (int s = 0; s < CS; ++s) {
    const int g = base + s * 256;
    gi[s] = g;
    const int gc = g < G ? g : G - 1;
    const int b = gc / NP;
    const int p = gc - b * NP;
    const int i = p / 14, j = p - i * 14;
    const float* px = x + (size_t)b * 784 + (2 * i) * 28 + 2 * j;
    const float2 r0 = *(const float2*)px;
    const float2 r1 = *(const float2*)(px + 28);
    const float mnv = smn[p], sc = ssc[p];
    float cc[4], ss[4];
    __sincosf((r0.x - mnv) * sc, &ss[0], &cc[0]);
    __sincosf((r0.y - mnv) * sc, &ss[1], &cc[1]);
    __sincosf((r1.x - mnv) * sc, &ss[2], &cc[2]);
    __sincosf((r1.y - mnv) * sc, &ss[3], &cc[3]);
    const float A[4] = {cc[0] * cc[1], cc[0] * ss[1], ss[0] * cc[1], ss[0] * ss[1]};
    const float Bq[4] = {cc[2] * cc[3], cc[2] * ss[3], ss[2] * cc[3], ss[2] * ss[3]};
#pragma unroll
    for (int idx = 0; idx < 16; ++idx) st[s][idx] = A[idx >> 2] * Bq[idx & 3];
  }

  float zz[CS][4];
#pragma unroll
  for (int s = 0; s < CS; ++s)
#pragma unroll
    for (int w = 0; w < 4; ++w) zz[s][w] = 0.f;

#pragma unroll
  for (int i2 = 0; i2 < 16; ++i2) {
    const float4 u0 = *(const float4*)&sU[i2 * 16 + 0];
    const float4 u1 = *(const float4*)&sU[i2 * 16 + 4];
    const float4 u2 = *(const float4*)&sU[i2 * 16 + 8];
    const float4 u3 = *(const float4*)&sU[i2 * 16 + 12];
#pragma unroll
    for (int s = 0; s < CS; ++s) {
      float f = u0.x * st[s][0];
      f = fmaf(u0.y, st[s][1], f);
      f = fmaf(u0.z, st[s][2], f);
      f = fmaf(u0.w, st[s][3], f);
      f = fmaf(u1.x, st[s][4], f);
      f = fmaf(u1.y, st[s][5], f);
      f = fmaf(u1.z, st[s][6], f);
      f = fmaf(u1.w, st[s][7], f);
      f = fmaf(u2.x, st[s][8], f);
      f = fmaf(u2.y, st[s][9], f);
      f = fmaf(u2.z, st[s][10], f);
      f = fmaf(u2.w, st[s][11], f);
      f = fmaf(u3.x, st[s][12], f);
      f = fmaf(u3.y, st[s][13], f);
      f = fmaf(u3.z, st[s][14], f);
      f = fmaf(u3.w, st[s][15], f);
      const float sq = f * f;
      zz[s][0] += (i2 & 8) ? -sq : sq;
      zz[s][1] += (i2 & 4) ? -sq : sq;
      zz[s][2] += (i2 & 2) ? -sq : sq;
      zz[s][3] += (i2 & 1) ? -sq : sq;
    }
  }
#pragma unroll
  for (int s = 0; s < CS; ++s)
    if (gi[s] < G) gmeas[gi[s]] = make_float4(zz[s][0], zz[s][1], zz[s][2], zz[s][3]);
}

// ---------------------------------------------------------------------------
// K3: classifier + residual + log_softmax. One wave per image; float4 loads.
// ---------------------------------------------------------------------------
__global__ void __launch_bounds__(256) cls_kernel(
    const float4* __restrict__ gmeas, const float* __restrict__ x,
    const float* __restrict__ W2, const float4* __restrict__ cls_w4,
    const float* __restrict__ cls_b, float* __restrict__ out, int B) {
  const int wv = (blockIdx.x * 256 + threadIdx.x) >> 6;
  const int lane = threadIdx.x & 63;
  if (wv >= B) return;  // wave-uniform
  const float4* mrow = gmeas + (size_t)wv * NP;
  const float* xrow = x + (size_t)wv * 784;

  float acc[10];
#pragma unroll
  for (int k = 0; k < 10; ++k) acc[k] = 0.f;

  for (int t4 = lane; t4 < NP; t4 += 64) {
    const float4 v = mrow[t4];
#pragma unroll
    for (int k = 0; k < 10; ++k) {
      const float4 w = cls_w4[k * NP + t4];
      acc[k] = fmaf(v.x, w.x, fmaf(v.y, w.y, fmaf(v.z, w.z, fmaf(v.w, w.w, acc[k]))));
    }
  }
  for (int p = lane; p < NP; p += 64) {
    const int i = p / 14, j = p - i * 14;
    const float v = xrow[(2 * i) * 28 + 2 * j];
#pragma unroll
    for (int k = 0; k < 10; ++k) acc[k] = fmaf(v, W2[k * NP + p], acc[k]);
  }
#pragma unroll
  for (int k = 0; k < 10; ++k) {
    float a = acc[k];
#pragma unroll
    for (int off = 32; off > 0; off >>= 1) a += __shfl_down(a, off, 64);
    acc[k] = a;
  }
  if (lane == 0) {
    float lg[10];
#pragma unroll
    for (int k = 0; k < 10; ++k) lg[k] = acc[k] + cls_b[k];
    float m = lg[0];
#pragma unroll
    for (int k = 1; k < 10; ++k) m = fmaxf(m, lg[k]);
    float s = 0.f;
#pragma unroll
    for (int k = 0; k < 10; ++k) s += __expf(lg[k] - m);
    const float lse = m + __logf(s);
#pragma unroll
    for (int k = 0; k < 10; ++k) out[(size_t)wv * 10 + k] = lg[k] - lse;
  }
}

extern "C" void kernel_launch(void* const* d_in, const int* in_sizes, int n_in,
                              void* d_out, int out_size, void* d_ws, size_t ws_size,
                              hipStream_t stream) {
  const float* x      = (const float*)d_in[0];
  const float* params = (const float*)d_in[1];
  const float* res_w  = (const float*)d_in[2];
  const float* cls_w  = (const float*)d_in[3];
  const float* cls_b  = (const float*)d_in[4];
  float* out = (float*)d_out;
  const int B = in_sizes[0] / 784;

  // ws layout: mn[196] u32 | mx[196] u32 | U[256] f32 | W2[1960] f32 | gmeas[B*784] f32
  unsigned* mn = (unsigned*)d_ws;
  unsigned* mx = mn + NP;
  float* U  = (float*)(mx + NP);
  float* W2 = U + 256;
  float* gmeas = W2 + 10 * NP;  // float offset 2608 -> 16B aligned

  precompute_kernel<<<8, 256, 0, stream>>>(params, res_w, cls_w, U, W2, mn, mx);

  const int imgs = 16;
  const int nblk1 = (B + imgs - 1) / imgs;
  minmax_kernel<<<nblk1, 256, 0, stream>>>(x, mn, mx, imgs, B);

  const int G = B * NP;
  const int nblk2 = (G + 256 * CS - 1) / (256 * CS);
  circuit_kernel<<<nblk2, 256, 0, stream>>>(x, mn, mx, U, (float4*)gmeas, G);

  cls_kernel<<<(B * 64 + 255) / 256, 256, 0, stream>>>((const float4*)gmeas, x, W2,
                                                       (const float4*)cls_w, cls_b, out, B);
}

// Round 5
// 131.223 us; speedup vs baseline: 1.1162x; 1.1162x over previous
//
#include <hip/hip_runtime.h>
#include <math.h>

#define NP 196
#define PI_F 3.14159265358979323846f

// order-preserving float<->uint encoding (monotone: min of keys == key of min)
__device__ __forceinline__ unsigned fkey(float f) {
  unsigned u = __float_as_uint(f);
  return u ^ ((unsigned)((int)u >> 31) | 0x80000000u);
}
__device__ __forceinline__ float funkey(unsigned k) {
  unsigned u = (k & 0x80000000u) ? (k ^ 0x80000000u) : ~k;
  return __uint_as_float(u);
}

// ---------------------------------------------------------------------------
// K0 (grid=8): block 0 computes U (16x16 circuit matrix) and inits mn/mx;
// all blocks fill W2[k,p] = sum_c res_w[c]*cls_w[k, c*196+p].
// ---------------------------------------------------------------------------
__global__ void __launch_bounds__(256) precompute_kernel(
    const float* __restrict__ params, const float* __restrict__ res_w,
    const float* __restrict__ cls_w, float* __restrict__ U,
    float* __restrict__ W2, unsigned* __restrict__ mn,
    unsigned* __restrict__ mx) {
  const int tid = threadIdx.x;
  if (blockIdx.x == 0) {
    if (tid < NP) { mn[tid] = 0xFFFFFFFFu; mx[tid] = 0u; }
    if (tid < 16) {
      float cp[12], sp[12];
#pragma unroll
      for (int l = 0; l < 12; ++l) __sincosf(0.5f * params[l], &sp[l], &cp[l]);
      float st[16];
#pragma unroll
      for (int i = 0; i < 16; ++i) st[i] = 0.f;
      st[tid] = 1.f;  // basis vector e_j -> column j of U
#pragma unroll
      for (int l = 0; l < 3; ++l) {
#pragma unroll
        for (int q = 0; q < 4; ++q) {
          const float cq = cp[l * 4 + q], sq = sp[l * 4 + q];
          const int m = 8 >> q;
#pragma unroll
          for (int idx = 0; idx < 16; ++idx) {
            if (idx & m) continue;
            float v0 = st[idx], v1 = st[idx | m];
            st[idx] = cq * v0 - sq * v1;
            st[idx | m] = sq * v0 + cq * v1;
          }
        }
#pragma unroll
        for (int q = 0; q < 3; ++q) {
          const int mc = 8 >> q, mt = 4 >> q;
#pragma unroll
          for (int idx = 0; idx < 16; ++idx) {
            if ((idx & mc) && !(idx & mt)) {
              float t0 = st[idx];
              st[idx] = st[idx | mt];
              st[idx | mt] = t0;
            }
          }
        }
      }
#pragma unroll
      for (int i = 0; i < 16; ++i) U[i * 16 + tid] = st[i];
    }
  }
  for (int t = blockIdx.x * 256 + tid; t < 10 * NP; t += 8 * 256) {
    int k = t / NP, p = t - k * NP;
    float s = 0.f;
#pragma unroll
    for (int c = 0; c < 4; ++c) s += res_w[c] * cls_w[k * 784 + c * NP + p];
    W2[t] = s;
  }
}

// ---------------------------------------------------------------------------
// K1: per-patch-position min/max. Thread t<196 owns one float4 slot of the
// 784-float image (fully coalesced), register-reduces over `imgs` images,
// LDS row-combine, one global atomic per patch per block.
// ---------------------------------------------------------------------------
__global__ void __launch_bounds__(256) minmax_kernel(
    const float* __restrict__ x, unsigned* __restrict__ mn,
    unsigned* __restrict__ mx, int imgs, int B) {
  __shared__ float pmn[392], pmx[392];  // [row r(0..27)][col-pair jj(0..13)]
  const int t = threadIdx.x;
  const int img0 = blockIdx.x * imgs;
  if (t < NP) {
    const float* base = x + (size_t)img0 * 784 + 4 * t;
    float mn0 = 3.4e38f, mx0 = -3.4e38f, mn1 = 3.4e38f, mx1 = -3.4e38f;
    const int nimg = (img0 + imgs <= B) ? imgs : (B - img0);
#pragma unroll 4
    for (int m = 0; m < nimg; ++m) {
      float4 v = *(const float4*)(base + (size_t)m * 784);
      mn0 = fminf(mn0, fminf(v.x, v.y));
      mx0 = fmaxf(mx0, fmaxf(v.x, v.y));
      mn1 = fminf(mn1, fminf(v.z, v.w));
      mx1 = fmaxf(mx1, fmaxf(v.z, v.w));
    }
    const int r = (4 * t) / 28;
    const int jj = ((4 * t) - 28 * r) >> 1;  // even: covers jj and jj+1
    pmn[r * 14 + jj] = mn0;
    pmx[r * 14 + jj] = mx0;
    pmn[r * 14 + jj + 1] = mn1;
    pmx[r * 14 + jj + 1] = mx1;
  }
  __syncthreads();
  if (t < NP) {
    const int i = t / 14, j = t - i * 14;
    const int f0 = (2 * i) * 14 + j, f1 = f0 + 14;
    atomicMin(&mn[t], fkey(fminf(pmn[f0], pmn[f1])));
    atomicMax(&mx[t], fkey(fmaxf(pmx[f0], pmx[f1])));
  }
}

// ---------------------------------------------------------------------------
// K2: one sample per thread. U staged in LDS (wave-uniform ds_read_b128
// broadcasts, conflict-free); per-patch min/scale in LDS. __launch_bounds__
// (256,6) caps VGPR ~85 so 6 waves/SIMD hide LDS latency (R4: 168 VGPR ->
// 3 waves -> 29% VALUBusy -> 57us; this is the fix).
// z_w via |f|^2 == 1 identity: acc only bit-clear rows, z = 2*acc - 1.
// gmeas[g] = float4(z0..z3) at g = b*196+p  (== ref flat order b*784+4p+w).
// ---------------------------------------------------------------------------
__global__ void __launch_bounds__(256, 6) circuit_kernel(
    const float* __restrict__ x, const unsigned* __restrict__ mnk,
    const unsigned* __restrict__ mxk, const float* __restrict__ Ug,
    float4* __restrict__ gmeas, int G) {
  __shared__ float sU[256];
  __shared__ float smn[NP], ssc[NP];
  const int tid = threadIdx.x;
  sU[tid] = Ug[tid];
  if (tid < NP) {
    const float mnv = funkey(mnk[tid]);
    const float mxv = funkey(mxk[tid]);
    smn[tid] = mnv;
    ssc[tid] = (0.5f * PI_F) / (mxv - mnv + 1e-8f);  // half-angle scale
  }
  __syncthreads();

  const int g = blockIdx.x * 256 + tid;
  if (g >= G) return;
  const int b = g / NP;
  const int p = g - b * NP;
  const int i = p / 14, j = p - i * 14;

  const float* px = x + (size_t)b * 784 + (2 * i) * 28 + 2 * j;
  const float2 r0 = *(const float2*)px;
  const float2 r1 = *(const float2*)(px + 28);
  const float mnv = smn[p], sc = ssc[p];

  float cc[4], ss[4];
  __sincosf((r0.x - mnv) * sc, &ss[0], &cc[0]);
  __sincosf((r0.y - mnv) * sc, &ss[1], &cc[1]);
  __sincosf((r1.x - mnv) * sc, &ss[2], &cc[2]);
  __sincosf((r1.y - mnv) * sc, &ss[3], &cc[3]);

  // product state; index bit (8>>q) = wire q
  float st[16];
  {
    const float A[4] = {cc[0] * cc[1], cc[0] * ss[1], ss[0] * cc[1], ss[0] * ss[1]};
    const float Bq[4] = {cc[2] * cc[3], cc[2] * ss[3], ss[2] * cc[3], ss[2] * ss[3]};
#pragma unroll
    for (int idx = 0; idx < 16; ++idx) st[idx] = A[idx >> 2] * Bq[idx & 3];
  }

  float z0 = 0.f, z1 = 0.f, z2 = 0.f, z3 = 0.f;
#pragma unroll
  for (int i2 = 0; i2 < 16; ++i2) {
    const float4 u0 = *(const float4*)&sU[i2 * 16 + 0];
    const float4 u1 = *(const float4*)&sU[i2 * 16 + 4];
    const float4 u2 = *(const float4*)&sU[i2 * 16 + 8];
    const float4 u3 = *(const float4*)&sU[i2 * 16 + 12];
    float f = u0.x * st[0];
    f = fmaf(u0.y, st[1], f);
    f = fmaf(u0.z, st[2], f);
    f = fmaf(u0.w, st[3], f);
    f = fmaf(u1.x, st[4], f);
    f = fmaf(u1.y, st[5], f);
    f = fmaf(u1.z, st[6], f);
    f = fmaf(u1.w, st[7], f);
    f = fmaf(u2.x, st[8], f);
    f = fmaf(u2.y, st[9], f);
    f = fmaf(u2.z, st[10], f);
    f = fmaf(u2.w, st[11], f);
    f = fmaf(u3.x, st[12], f);
    f = fmaf(u3.y, st[13], f);
    f = fmaf(u3.z, st[14], f);
    f = fmaf(u3.w, st[15], f);
    // accumulate f^2 only where the wire-bit is CLEAR; z = 2*acc-1 at the end
    if (!(i2 & 8)) z0 = fmaf(f, f, z0);
    if (!(i2 & 4)) z1 = fmaf(f, f, z1);
    if (!(i2 & 2)) z2 = fmaf(f, f, z2);
    if (!(i2 & 1)) z3 = fmaf(f, f, z3);
  }
  gmeas[g] = make_float4(fmaf(2.f, z0, -1.f), fmaf(2.f, z1, -1.f),
                         fmaf(2.f, z2, -1.f), fmaf(2.f, z3, -1.f));
}

// ---------------------------------------------------------------------------
// K3: classifier + residual + log_softmax. One wave per image; float4 loads.
// ---------------------------------------------------------------------------
__global__ void __launch_bounds__(256) cls_kernel(
    const float4* __restrict__ gmeas, const float* __restrict__ x,
    const float* __restrict__ W2, const float4* __restrict__ cls_w4,
    const float* __restrict__ cls_b, float* __restrict__ out, int B) {
  const int wv = (blockIdx.x * 256 + threadIdx.x) >> 6;
  const int lane = threadIdx.x & 63;
  if (wv >= B) return;  // wave-uniform
  const float4* mrow = gmeas + (size_t)wv * NP;
  const float* xrow = x + (size_t)wv * 784;

  float acc[10];
#pragma unroll
  for (int k = 0; k < 10; ++k) acc[k] = 0.f;

  for (int t4 = lane; t4 < NP; t4 += 64) {
    const float4 v = mrow[t4];
#pragma unroll
    for (int k = 0; k < 10; ++k) {
      const float4 w = cls_w4[k * NP + t4];
      acc[k] = fmaf(v.x, w.x, fmaf(v.y, w.y, fmaf(v.z, w.z, fmaf(v.w, w.w, acc[k]))));
    }
  }
  for (int p = lane; p < NP; p += 64) {
    const int i = p / 14, j = p - i * 14;
    const float v = xrow[(2 * i) * 28 + 2 * j];
#pragma unroll
    for (int k = 0; k < 10; ++k) acc[k] = fmaf(v, W2[k * NP + p], acc[k]);
  }
#pragma unroll
  for (int k = 0; k < 10; ++k) {
    float a = acc[k];
#pragma unroll
    for (int off = 32; off > 0; off >>= 1) a += __shfl_down(a, off, 64);
    acc[k] = a;
  }
  if (lane == 0) {
    float lg[10];
#pragma unroll
    for (int k = 0; k < 10; ++k) lg[k] = acc[k] + cls_b[k];
    float m = lg[0];
#pragma unroll
    for (int k = 1; k < 10; ++k) m = fmaxf(m, lg[k]);
    float s = 0.f;
#pragma unroll
    for (int k = 0; k < 10; ++k) s += __expf(lg[k] - m);
    const float lse = m + __logf(s);
#pragma unroll
    for (int k = 0; k < 10; ++k) out[(size_t)wv * 10 + k] = lg[k] - lse;
  }
}

extern "C" void kernel_launch(void* const* d_in, const int* in_sizes, int n_in,
                              void* d_out, int out_size, void* d_ws, size_t ws_size,
                              hipStream_t stream) {
  const float* x      = (const float*)d_in[0];
  const float* params = (const float*)d_in[1];
  const float* res_w  = (const float*)d_in[2];
  const float* cls_w  = (const float*)d_in[3];
  const float* cls_b  = (const float*)d_in[4];
  float* out = (float*)d_out;
  const int B = in_sizes[0] / 784;

  // ws layout: mn[196] u32 | mx[196] u32 | U[256] f32 | W2[1960] f32 | gmeas[B*784] f32
  unsigned* mn = (unsigned*)d_ws;
  unsigned* mx = mn + NP;
  float* U  = (float*)(mx + NP);
  float* W2 = U + 256;
  float* gmeas = W2 + 10 * NP;  // float offset 2608 -> 16B aligned

  precompute_kernel<<<8, 256, 0, stream>>>(params, res_w, cls_w, U, W2, mn, mx);

  const int imgs = 16;
  const int nblk1 = (B + imgs - 1) / imgs;
  minmax_kernel<<<nblk1, 256, 0, stream>>>(x, mn, mx, imgs, B);

  const int G = B * NP;
  circuit_kernel<<<(G + 255) / 256, 256, 0, stream>>>(x, mn, mx, U, (float4*)gmeas, G);

  cls_kernel<<<(B * 64 + 255) / 256, 256, 0, stream>>>((const float4*)gmeas, x, W2,
                                                       (const float4*)cls_w, cls_b, out, B);
}